// Round 6
// baseline (330.224 us; speedup 1.0000x reference)
//
#include <hip/hip_runtime.h>
#include <hip/hip_bf16.h>
#include <cstdint>
#include <cstddef>

#define B_ 2
#define S_ 2048
#define D_ 2048
#define H_ 32
#define KVH_ 8
#define HD_ 64
#define PROJN 3072   // Q_OUT(2048) + 2*KV_OUT(512)

typedef unsigned short u16;
typedef unsigned int u32;
typedef __attribute__((ext_vector_type(8))) short short8;
typedef __attribute__((ext_vector_type(4))) short short4v;
typedef __attribute__((ext_vector_type(4))) float f32x4;

__device__ __forceinline__ u16 f2bf(float f) {
  __hip_bfloat16 h = __float2bfloat16(f);
  return *reinterpret_cast<u16*>(&h);
}

#define GLDS16(g, l)                                                           \
  __builtin_amdgcn_global_load_lds(                                            \
      (const __attribute__((address_space(1))) void*)(g),                      \
      (__attribute__((address_space(3))) void*)(l), 16, 0, 0)

// ---------------- pack f32 -> bf16 ----------------
__global__ __launch_bounds__(256) void pack_bf16(const float* __restrict__ in,
                                                 u16* __restrict__ out, int n) {
  int i = (blockIdx.x * 256 + threadIdx.x) * 8;
  if (i >= n) return;
  const float4* p = reinterpret_cast<const float4*>(in + i);
  float4 a = p[0], b = p[1];
  union { short8 v; u16 u[8]; } r;
  r.u[0] = f2bf(a.x); r.u[1] = f2bf(a.y); r.u[2] = f2bf(a.z); r.u[3] = f2bf(a.w);
  r.u[4] = f2bf(b.x); r.u[5] = f2bf(b.y); r.u[6] = f2bf(b.z); r.u[7] = f2bf(b.w);
  *reinterpret_cast<short8*>(out + i) = r.v;
}

// ---------------- rope cos/sin table ----------------
__global__ __launch_bounds__(256) void rope_table(float* __restrict__ tc,
                                                  float* __restrict__ ts) {
  int i = blockIdx.x * 256 + threadIdx.x;  // S_*32
  int s = i >> 5, j = i & 31;
  float e = (float)(2 * j) / 64.0f;
  float inv_freq = 1.0f / powf(10000.0f, e);
  float ang = (float)s * inv_freq;
  tc[i] = cosf(ang);
  ts[i] = sinf(ang);
}

// ---------------- bf16 GEMM: C[M,N] = A[M,K] * Bw[N,K]^T ----------------
__global__ __launch_bounds__(256) void gemm_bt(const u16* __restrict__ A,
                                               const u16* __restrict__ Bw,
                                               float* __restrict__ C, int M,
                                               int N, int K) {
  __shared__ u16 As[128 * 64];
  __shared__ u16 Bs[128 * 64];
  const int tid = threadIdx.x;
  const int lane = tid & 63;
  const int wave = tid >> 6;
  const int ntile = N >> 7;
  const int m0 = (blockIdx.x / ntile) << 7;
  const int n0 = (blockIdx.x % ntile) << 7;
  const int wr = (wave >> 1) << 6;
  const int wc = (wave & 1) << 6;
  const int arow = lane & 15;
  const int kgrp = lane >> 4;

  const f32x4 zero4 = {0.f, 0.f, 0.f, 0.f};
  f32x4 acc[4][4];
#pragma unroll
  for (int m = 0; m < 4; m++)
#pragma unroll
    for (int n = 0; n < 4; n++) acc[m][n] = zero4;

  int srow[4], sslot[4];
#pragma unroll
  for (int i = 0; i < 4; i++) {
    int c = i * 256 + tid;
    srow[i] = c >> 3;
    sslot[i] = (c & 7) ^ (srow[i] & 7);  // inverse-swizzled source slot
  }

  auto stage = [&](int kt) {
    const int k0 = kt << 6;
#pragma unroll
    for (int i = 0; i < 4; i++) {
      const u16* ga = A + (size_t)(m0 + srow[i]) * K + k0 + sslot[i] * 8;
      GLDS16(ga, As + (i * 256 + tid) * 8);
    }
#pragma unroll
    for (int i = 0; i < 4; i++) {
      const u16* gb = Bw + (size_t)(n0 + srow[i]) * K + k0 + sslot[i] * 8;
      GLDS16(gb, Bs + (i * 256 + tid) * 8);
    }
  };

  const int KT = K >> 6;
  stage(0);
  for (int kt = 0;; kt++) {
    __syncthreads();  // staging drained (compiler emits vmcnt(0) before barrier)
#pragma unroll
    for (int ks = 0; ks < 2; ks++) {
      const int sd = ks * 4 + kgrp;
      short8 a[4], b[4];
#pragma unroll
      for (int m = 0; m < 4; m++) {
        int r = wr + m * 16 + arow;
        a[m] = *reinterpret_cast<const short8*>(As + r * 64 + ((sd ^ (r & 7)) << 3));
      }
#pragma unroll
      for (int n = 0; n < 4; n++) {
        int r = wc + n * 16 + arow;
        b[n] = *reinterpret_cast<const short8*>(Bs + r * 64 + ((sd ^ (r & 7)) << 3));
      }
#pragma unroll
      for (int m = 0; m < 4; m++)
#pragma unroll
        for (int n = 0; n < 4; n++)
          acc[m][n] = __builtin_amdgcn_mfma_f32_16x16x32_bf16(a[m], b[n], acc[m][n], 0, 0, 0);
    }
    if (kt + 1 == KT) break;
    __syncthreads();
    stage(kt + 1);
  }

  const int crow = kgrp * 4;
#pragma unroll
  for (int m = 0; m < 4; m++) {
#pragma unroll
    for (int n = 0; n < 4; n++) {
      float* cp = C + (size_t)(m0 + wr + m * 16 + crow) * N + n0 + wc + n * 16 + arow;
#pragma unroll
      for (int r = 0; r < 4; r++) cp[(size_t)r * N] = acc[m][n][r];
    }
  }
}

// ---------------- RoPE + RMSNorm for Q and K ----------------
// one wave per (b, s, head'), head' in [0,40): 0..31 Q heads, 32..39 K heads
__global__ __launch_bounds__(256) void rope_norm(
    const float* __restrict__ proj, const float* __restrict__ tc,
    const float* __restrict__ ts, const float* __restrict__ gain,
    u16* __restrict__ Qn, u16* __restrict__ Kn) {
  int wid = (blockIdx.x * 256 + threadIdx.x) >> 6;  // B_*S_*40 waves
  int lane = threadIdx.x & 63;
  int hh = wid % 40;
  int bs = wid / 40;  // b*S_ + s
  int s = bs & (S_ - 1);
  int b = bs >> 11;
  int off = hh < 32 ? hh * 64 + lane : 2048 + (hh - 32) * 64 + lane;
  float val = proj[(size_t)bs * PROJN + off];
  int j = lane & 31;
  float c = tc[s * 32 + j], sn = ts[s * 32 + j];
  float partner = __shfl_xor(val, 32);
  float out = lane < 32 ? val * c - partner * sn : val * c + partner * sn;
  float ss = out * out;
#pragma unroll
  for (int m = 32; m >= 1; m >>= 1) ss += __shfl_xor(ss, m);
  float inv = rsqrtf(ss * (1.0f / 64.0f) + 1e-6f);
  float g = hh < 32 ? gain[0] : 1.0f;
  u16 ub = f2bf(out * inv * g);
  if (hh < 32)
    Qn[(((size_t)(b * H_ + hh)) * S_ + s) * HD_ + lane] = ub;
  else
    Kn[(((size_t)(b * KVH_ + (hh - 32))) * S_ + s) * HD_ + lane] = ub;
}

// ---------------- V: transpose to (B,KVH,HD,S) bf16 + V_flat f32 output ----------------
__global__ __launch_bounds__(256) void vtrans(const float* __restrict__ proj,
                                              u16* __restrict__ Vt,
                                              float* __restrict__ Vout) {
  __shared__ float tile[64][65];
  const int bid = blockIdx.x;  // B_*KVH_*(S_/64)
  const int st = bid & 31;
  const int s0 = st << 6;
  const int kvh = (bid >> 5) & 7;
  const int b = bid >> 8;
  const int t = threadIdx.x;
  const int sr = t >> 2;
  const int d0 = (t & 3) << 4;
  const float* src = proj + ((size_t)(b * S_ + s0 + sr)) * PROJN + 2560 + kvh * 64 + d0;
  float v[16];
#pragma unroll
  for (int i = 0; i < 16; i += 4) {
    float4 x = *reinterpret_cast<const float4*>(src + i);
    v[i] = x.x; v[i + 1] = x.y; v[i + 2] = x.z; v[i + 3] = x.w;
  }
  // V_flat output: rows h*B+b, 4 repeated heads (scale rsqrt(1+1e-8) == 1.0f exactly)
#pragma unroll
  for (int hh = 0; hh < 4; hh++) {
    int hq = kvh * 4 + hh;
    float* dst = Vout + (((size_t)(hq * B_ + b)) * S_ + s0 + sr) * HD_ + d0;
#pragma unroll
    for (int i = 0; i < 16; i += 4)
      *reinterpret_cast<float4*>(dst + i) = make_float4(v[i], v[i + 1], v[i + 2], v[i + 3]);
  }
#pragma unroll
  for (int i = 0; i < 16; i++) tile[sr][d0 + i] = v[i];
  __syncthreads();
  const int d = t >> 2;
  const int sc = (t & 3) << 4;
  union { short8 v8; u16 u[8]; } o0, o1;
#pragma unroll
  for (int i = 0; i < 8; i++) o0.u[i] = f2bf(tile[sc + i][d]);
#pragma unroll
  for (int i = 0; i < 8; i++) o1.u[i] = f2bf(tile[sc + 8 + i][d]);
  u16* dst = Vt + (((size_t)(b * KVH_ + kvh)) * HD_ + d) * S_ + s0 + sc;
  *reinterpret_cast<short8*>(dst) = o0.v8;
  *reinterpret_cast<short8*>(dst + 8) = o1.v8;
}

// ---------------- flash attention (causal, GQA) ----------------
// Block = (b, kvh, q-tile PAIR {u, 63-u}): uniform 32-34 iterations per block,
// zero tail. Wave w = head kvh*4+w, owns 2x32 q-rows (4 Q-frags: ff<2 tile A,
// ff>=2 tile B; A retires at JT_A). K/V double-buffered, 1 barrier/tile,
// stage-early. FIXED-C softmax: RMSNorm => |q.k|*scale*log2e <= 11.54 < 12
// (gain==1), so p = exp2(s*SCL2E - 12) needs NO running max / rescale; the
// softmax ratio is scale-invariant => identical result. Denominator reduced
// once after the loop.
__global__ __launch_bounds__(256, 2) void attn_fwd(const u16* __restrict__ Qn,
                                                   const u16* __restrict__ Kn,
                                                   const u16* __restrict__ Vt,
                                                   u16* __restrict__ Aout) {
  __shared__ u16 Ks[2][64 * 64];
  __shared__ u16 Vs[2][64 * 64];
  __shared__ u16 Ps[4][4][1024];  // [wave][frag][16 q-rows x 64 kv]
  const int bid = blockIdx.x;     // B_*KVH_*32
  const int u = bid & 31;
  const int kvh = (bid >> 5) & 7;
  const int b = bid >> 8;
  const int q0A = u << 5;
  const int q0B = (63 - u) << 5;
  const int JT_A = (u >> 1) + 1;
  const int JT_B = 32 - (u >> 1);
  const int tid = threadIdx.x;
  const int lane = tid & 63;
  const int wave = tid >> 6;
  const int h = kvh * 4 + wave;  // this wave's Q head
  const int ql = lane & 15;
  const int g = lane >> 4;
  const float SCL2E = 0.125f * 1.44269504088896340736f;

  // Q frags: ff=0,1 -> tile A rows q0A+16*ff+ql; ff=2,3 -> tile B
  short8 qa[4][2];
  int rowq[4];
#pragma unroll
  for (int ff = 0; ff < 4; ff++) {
    const int q0 = (ff < 2) ? q0A : q0B;
    rowq[ff] = q0 + 16 * (ff & 1) + ql;
    const u16* qb = Qn + (((size_t)(b * H_ + h)) * S_ + rowq[ff]) * HD_;
    qa[ff][0] = *reinterpret_cast<const short8*>(qb + g * 8);
    qa[ff][1] = *reinterpret_cast<const short8*>(qb + 32 + g * 8);
  }

  const f32x4 zero4 = {0.f, 0.f, 0.f, 0.f};
  f32x4 oacc[4][4];  // [dn][ff]
#pragma unroll
  for (int dn = 0; dn < 4; dn++)
#pragma unroll
    for (int ff = 0; ff < 4; ff++) oacc[dn][ff] = zero4;
  float psum[4] = {0.f, 0.f, 0.f, 0.f};

  const u16* kg = Kn + ((size_t)(b * KVH_ + kvh)) * S_ * HD_;
  const u16* vg = Vt + ((size_t)(b * KVH_ + kvh)) * HD_ * S_;

  const int c0 = tid, c1 = 256 + tid;
  const int r0 = c0 >> 3, sl0 = (c0 & 7) ^ (r0 & 7);
  const int r1 = c1 >> 3, sl1 = (c1 & 7) ^ (r1 & 7);
  const int xsw2 = (ql & 7) << 2;

  auto stage = [&](int jt, int buf) {
    const int j0 = jt << 6;
    GLDS16(kg + (size_t)(j0 + r0) * HD_ + sl0 * 8, Ks[buf] + c0 * 8);
    GLDS16(kg + (size_t)(j0 + r1) * HD_ + sl1 * 8, Ks[buf] + c1 * 8);
    GLDS16(vg + (size_t)r0 * S_ + j0 + sl0 * 8, Vs[buf] + c0 * 8);
    GLDS16(vg + (size_t)r1 * S_ + j0 + sl1 * 8, Vs[buf] + c1 * 8);
  };

  stage(0, 0);
  __syncthreads();  // drain prologue stage
  int cur = 0;
  for (int jt = 0; jt < JT_B; jt++) {
    if (jt + 1 < JT_B) stage(jt + 1, cur ^ 1);  // issue next tile early
    const int j0 = jt << 6;
    const u16* ksb = Ks[cur];
    const u16* vsb = Vs[cur];
    const bool actA = (jt < JT_A);

    // per q-tile pair: S^T = K·Q^T, then p = exp2(fma(s,SCL2E,-12)), pack->LDS
#pragma unroll
    for (int p = 0; p < 2; p++) {
      if (p == 0 && !actA) continue;
      f32x4 sc[4][2];
#pragma unroll
      for (int n = 0; n < 4; n++)
#pragma unroll
        for (int f = 0; f < 2; f++) sc[n][f] = zero4;
      __builtin_amdgcn_s_setprio(1);
#pragma unroll
      for (int ks = 0; ks < 2; ks++) {
        const int sd = ks * 4 + g;
#pragma unroll
        for (int n = 0; n < 4; n++) {
          const int r = n * 16 + ql;
          short8 kf = *reinterpret_cast<const short8*>(ksb + r * 64 + ((sd ^ (r & 7)) << 3));
          sc[n][0] = __builtin_amdgcn_mfma_f32_16x16x32_bf16(kf, qa[2 * p][ks], sc[n][0], 0, 0, 0);
          sc[n][1] = __builtin_amdgcn_mfma_f32_16x16x32_bf16(kf, qa[2 * p + 1][ks], sc[n][1], 0, 0, 0);
        }
      }
      __builtin_amdgcn_s_setprio(0);
#pragma unroll
      for (int f = 0; f < 2; f++) {
        const int ff = 2 * p + f;
        const int jtEnd = (p == 0) ? JT_A : JT_B;
        const bool diag = (jt == jtEnd - 1);
        float pv[4][4];
#pragma unroll
        for (int n = 0; n < 4; n++)
#pragma unroll
          for (int r = 0; r < 4; r++)
            pv[n][r] = exp2f(fmaf(sc[n][f][r], SCL2E, -12.0f));
        if (diag) {
#pragma unroll
          for (int n = 0; n < 4; n++)
#pragma unroll
            for (int r = 0; r < 4; r++)
              if ((j0 + n * 16 + 4 * g + r) > rowq[ff]) pv[n][r] = 0.f;
        }
        u32* pw32 = reinterpret_cast<u32*>(Ps[wave][ff]);
#pragma unroll
        for (int n = 0; n < 4; n++) {
          psum[ff] += (pv[n][0] + pv[n][1]) + (pv[n][2] + pv[n][3]);
          union { u32 w; u16 hh[2]; } c01, c23;
          c01.hh[0] = f2bf(pv[n][0]); c01.hh[1] = f2bf(pv[n][1]);
          c23.hh[0] = f2bf(pv[n][2]); c23.hh[1] = f2bf(pv[n][3]);
          const int idx = ql * 32 + (((n << 3) + (g << 1)) ^ xsw2);
          pw32[idx] = c01.w;
          pw32[idx + 1] = c23.w;
        }
      }
    }

    // read all P-frags (single LDS drain), then PV for all frags
    short8 pa[4][2];
#pragma unroll
    for (int ff = 0; ff < 4; ff++) {
      if (ff < 2 && !actA) continue;
#pragma unroll
      for (int ks = 0; ks < 2; ks++)
        pa[ff][ks] = *reinterpret_cast<const short8*>(
            Ps[wave][ff] + ql * 64 + ((32 * ks + 8 * g) ^ (xsw2 << 1)));
    }
    __builtin_amdgcn_s_setprio(1);
#pragma unroll
    for (int ks = 0; ks < 2; ks++) {
      const int sd = ks * 4 + g;
#pragma unroll
      for (int dn = 0; dn < 4; dn++) {
        const int vr = dn * 16 + ql;
        short8 vf = *reinterpret_cast<const short8*>(vsb + vr * 64 + ((sd ^ (vr & 7)) << 3));
        if (actA) {
          oacc[dn][0] = __builtin_amdgcn_mfma_f32_16x16x32_bf16(vf, pa[0][ks], oacc[dn][0], 0, 0, 0);
          oacc[dn][1] = __builtin_amdgcn_mfma_f32_16x16x32_bf16(vf, pa[1][ks], oacc[dn][1], 0, 0, 0);
        }
        oacc[dn][2] = __builtin_amdgcn_mfma_f32_16x16x32_bf16(vf, pa[2][ks], oacc[dn][2], 0, 0, 0);
        oacc[dn][3] = __builtin_amdgcn_mfma_f32_16x16x32_bf16(vf, pa[3][ks], oacc[dn][3], 0, 0, 0);
      }
    }
    __builtin_amdgcn_s_setprio(0);

    __syncthreads();  // stage(jt+1) drained + all reads of buf[cur] done
    cur ^= 1;
  }

  // final denominator reduce (once) + output
#pragma unroll
  for (int ff = 0; ff < 4; ff++) {
    float s = psum[ff];
    s += __shfl_xor(s, 16);
    s += __shfl_xor(s, 32);
    const float il = 1.0f / s;
#pragma unroll
    for (int dn = 0; dn < 4; dn++) {
      union { short4v v; u16 uu[4]; } o;
#pragma unroll
      for (int r = 0; r < 4; r++) o.uu[r] = f2bf(oacc[dn][ff][r] * il);
      u16* dst = Aout + ((size_t)b * S_ + rowq[ff]) * D_ + h * HD_ + dn * 16 + 4 * g;
      *reinterpret_cast<short4v*>(dst) = o.v;
    }
  }
}

// ---------------- launcher ----------------
extern "C" void kernel_launch(void* const* d_in, const int* in_sizes, int n_in,
                              void* d_out, int out_size, void* d_ws,
                              size_t ws_size, hipStream_t stream) {
  const float* x = (const float*)d_in[0];
  const float* wqkv = (const float*)d_in[1];
  const float* wout = (const float*)d_in[2];
  const float* gain = (const float*)d_in[3];

  float* out_attn = (float*)d_out;                       // (B,S,D) f32
  float* out_vflat = out_attn + (size_t)B_ * S_ * D_;    // (H*B,S,HD) f32

  uint8_t* w = (uint8_t*)d_ws;
  u16* xb     = (u16*)(w);                      // 16,777,216 B
  u16* wqkvb  = (u16*)(w + 16777216);           // 12,582,912 B
  u16* woutb  = (u16*)(w + 29360128);           //  8,388,608 B
  float* proj = (float*)(w + 37748736);         // 50,331,648 B
  u16* Qn     = (u16*)(w + 88080384);           // 16,777,216 B
  u16* Kn     = (u16*)(w + 104857600);          //  4,194,304 B
  u16* Vt     = (u16*)(w + 109051904);          //  4,194,304 B
  u16* attnb  = (u16*)(w + 113246208);          // 16,777,216 B
  float* tc   = (float*)(w + 130023424);        //    262,144 B
  float* ts   = (float*)(w + 130285568);        //    262,144 B
  // total: 130,547,712 B

  pack_bf16<<<4096, 256, 0, stream>>>(x, xb, B_ * S_ * D_);
  pack_bf16<<<3072, 256, 0, stream>>>(wqkv, wqkvb, PROJN * D_);
  pack_bf16<<<2048, 256, 0, stream>>>(wout, woutb, D_ * D_);
  rope_table<<<256, 256, 0, stream>>>(tc, ts);

  // proj = x @ w_qkv^T : (4096 x 3072)
  gemm_bt<<<(4096 / 128) * (3072 / 128), 256, 0, stream>>>(xb, wqkvb, proj,
                                                           4096, PROJN, 2048);
  rope_norm<<<(B_ * S_ * 40) / 4, 256, 0, stream>>>(proj, tc, ts, gain, Qn, Kn);
  vtrans<<<B_ * KVH_ * (S_ / 64), 256, 0, stream>>>(proj, Vt, out_vflat);
  attn_fwd<<<B_ * KVH_ * (S_ / 32), 256, 0, stream>>>(Qn, Kn, Vt, attnb);
  // attn_out = attn @ w_out^T : (4096 x 2048)
  gemm_bt<<<(4096 / 128) * (2048 / 128), 256, 0, stream>>>(attnb, woutb,
                                                           out_attn, 4096,
                                                           2048, 2048);
}

// Round 7
// 253.305 us; speedup vs baseline: 1.3037x; 1.3037x over previous
//
#include <hip/hip_runtime.h>
#include <hip/hip_bf16.h>
#include <cstdint>
#include <cstddef>

#define B_ 2
#define S_ 2048
#define D_ 2048
#define H_ 32
#define KVH_ 8
#define HD_ 64
#define PROJN 3072   // Q_OUT(2048) + 2*KV_OUT(512)

typedef unsigned short u16;
typedef unsigned int u32;
typedef __attribute__((ext_vector_type(8))) short short8;
typedef __attribute__((ext_vector_type(4))) short short4v;
typedef __attribute__((ext_vector_type(4))) float f32x4;

__device__ __forceinline__ u16 f2bf(float f) {
  __hip_bfloat16 h = __float2bfloat16(f);
  return *reinterpret_cast<u16*>(&h);
}

#define GLDS16(g, l)                                                           \
  __builtin_amdgcn_global_load_lds(                                            \
      (const __attribute__((address_space(1))) void*)(g),                      \
      (__attribute__((address_space(3))) void*)(l), 16, 0, 0)

// ---------------- pack f32 -> bf16 ----------------
__global__ __launch_bounds__(256) void pack_bf16(const float* __restrict__ in,
                                                 u16* __restrict__ out, int n) {
  int i = (blockIdx.x * 256 + threadIdx.x) * 8;
  if (i >= n) return;
  const float4* p = reinterpret_cast<const float4*>(in + i);
  float4 a = p[0], b = p[1];
  union { short8 v; u16 u[8]; } r;
  r.u[0] = f2bf(a.x); r.u[1] = f2bf(a.y); r.u[2] = f2bf(a.z); r.u[3] = f2bf(a.w);
  r.u[4] = f2bf(b.x); r.u[5] = f2bf(b.y); r.u[6] = f2bf(b.z); r.u[7] = f2bf(b.w);
  *reinterpret_cast<short8*>(out + i) = r.v;
}

// ---------------- rope cos/sin table ----------------
__global__ __launch_bounds__(256) void rope_table(float* __restrict__ tc,
                                                  float* __restrict__ ts) {
  int i = blockIdx.x * 256 + threadIdx.x;  // S_*32
  int s = i >> 5, j = i & 31;
  float e = (float)(2 * j) / 64.0f;
  float inv_freq = 1.0f / powf(10000.0f, e);
  float ang = (float)s * inv_freq;
  tc[i] = cosf(ang);
  ts[i] = sinf(ang);
}

// ---------------- bf16 GEMM: C[M,N] = A[M,K] * Bw[N,K]^T ----------------
__global__ __launch_bounds__(256) void gemm_bt(const u16* __restrict__ A,
                                               const u16* __restrict__ Bw,
                                               float* __restrict__ C, int M,
                                               int N, int K) {
  __shared__ u16 As[128 * 64];
  __shared__ u16 Bs[128 * 64];
  const int tid = threadIdx.x;
  const int lane = tid & 63;
  const int wave = tid >> 6;
  const int ntile = N >> 7;
  const int m0 = (blockIdx.x / ntile) << 7;
  const int n0 = (blockIdx.x % ntile) << 7;
  const int wr = (wave >> 1) << 6;
  const int wc = (wave & 1) << 6;
  const int arow = lane & 15;
  const int kgrp = lane >> 4;

  const f32x4 zero4 = {0.f, 0.f, 0.f, 0.f};
  f32x4 acc[4][4];
#pragma unroll
  for (int m = 0; m < 4; m++)
#pragma unroll
    for (int n = 0; n < 4; n++) acc[m][n] = zero4;

  int srow[4], sslot[4];
#pragma unroll
  for (int i = 0; i < 4; i++) {
    int c = i * 256 + tid;
    srow[i] = c >> 3;
    sslot[i] = (c & 7) ^ (srow[i] & 7);  // inverse-swizzled source slot
  }

  auto stage = [&](int kt) {
    const int k0 = kt << 6;
#pragma unroll
    for (int i = 0; i < 4; i++) {
      const u16* ga = A + (size_t)(m0 + srow[i]) * K + k0 + sslot[i] * 8;
      GLDS16(ga, As + (i * 256 + tid) * 8);
    }
#pragma unroll
    for (int i = 0; i < 4; i++) {
      const u16* gb = Bw + (size_t)(n0 + srow[i]) * K + k0 + sslot[i] * 8;
      GLDS16(gb, Bs + (i * 256 + tid) * 8);
    }
  };

  const int KT = K >> 6;
  stage(0);
  for (int kt = 0;; kt++) {
    __syncthreads();  // staging drained (compiler emits vmcnt(0) before barrier)
#pragma unroll
    for (int ks = 0; ks < 2; ks++) {
      const int sd = ks * 4 + kgrp;
      short8 a[4], b[4];
#pragma unroll
      for (int m = 0; m < 4; m++) {
        int r = wr + m * 16 + arow;
        a[m] = *reinterpret_cast<const short8*>(As + r * 64 + ((sd ^ (r & 7)) << 3));
      }
#pragma unroll
      for (int n = 0; n < 4; n++) {
        int r = wc + n * 16 + arow;
        b[n] = *reinterpret_cast<const short8*>(Bs + r * 64 + ((sd ^ (r & 7)) << 3));
      }
#pragma unroll
      for (int m = 0; m < 4; m++)
#pragma unroll
        for (int n = 0; n < 4; n++)
          acc[m][n] = __builtin_amdgcn_mfma_f32_16x16x32_bf16(a[m], b[n], acc[m][n], 0, 0, 0);
    }
    if (kt + 1 == KT) break;
    __syncthreads();
    stage(kt + 1);
  }

  const int crow = kgrp * 4;
#pragma unroll
  for (int m = 0; m < 4; m++) {
#pragma unroll
    for (int n = 0; n < 4; n++) {
      float* cp = C + (size_t)(m0 + wr + m * 16 + crow) * N + n0 + wc + n * 16 + arow;
#pragma unroll
      for (int r = 0; r < 4; r++) cp[(size_t)r * N] = acc[m][n][r];
    }
  }
}

// ---------------- RoPE + RMSNorm for Q and K ----------------
// one wave per (b, s, head'), head' in [0,40): 0..31 Q heads, 32..39 K heads
__global__ __launch_bounds__(256) void rope_norm(
    const float* __restrict__ proj, const float* __restrict__ tc,
    const float* __restrict__ ts, const float* __restrict__ gain,
    u16* __restrict__ Qn, u16* __restrict__ Kn) {
  int wid = (blockIdx.x * 256 + threadIdx.x) >> 6;  // B_*S_*40 waves
  int lane = threadIdx.x & 63;
  int hh = wid % 40;
  int bs = wid / 40;  // b*S_ + s
  int s = bs & (S_ - 1);
  int b = bs >> 11;
  int off = hh < 32 ? hh * 64 + lane : 2048 + (hh - 32) * 64 + lane;
  float val = proj[(size_t)bs * PROJN + off];
  int j = lane & 31;
  float c = tc[s * 32 + j], sn = ts[s * 32 + j];
  float partner = __shfl_xor(val, 32);
  float out = lane < 32 ? val * c - partner * sn : val * c + partner * sn;
  float ss = out * out;
#pragma unroll
  for (int m = 32; m >= 1; m >>= 1) ss += __shfl_xor(ss, m);
  float inv = rsqrtf(ss * (1.0f / 64.0f) + 1e-6f);
  float g = hh < 32 ? gain[0] : 1.0f;
  u16 ub = f2bf(out * inv * g);
  if (hh < 32)
    Qn[(((size_t)(b * H_ + hh)) * S_ + s) * HD_ + lane] = ub;
  else
    Kn[(((size_t)(b * KVH_ + (hh - 32))) * S_ + s) * HD_ + lane] = ub;
}

// ---------------- V: transpose to (B,KVH,HD,S) bf16 + V_flat f32 output ----------------
__global__ __launch_bounds__(256) void vtrans(const float* __restrict__ proj,
                                              u16* __restrict__ Vt,
                                              float* __restrict__ Vout) {
  __shared__ float tile[64][65];
  const int bid = blockIdx.x;  // B_*KVH_*(S_/64)
  const int st = bid & 31;
  const int s0 = st << 6;
  const int kvh = (bid >> 5) & 7;
  const int b = bid >> 8;
  const int t = threadIdx.x;
  const int sr = t >> 2;
  const int d0 = (t & 3) << 4;
  const float* src = proj + ((size_t)(b * S_ + s0 + sr)) * PROJN + 2560 + kvh * 64 + d0;
  float v[16];
#pragma unroll
  for (int i = 0; i < 16; i += 4) {
    float4 x = *reinterpret_cast<const float4*>(src + i);
    v[i] = x.x; v[i + 1] = x.y; v[i + 2] = x.z; v[i + 3] = x.w;
  }
  // V_flat output: rows h*B+b, 4 repeated heads (scale rsqrt(1+1e-8) == 1.0f exactly)
#pragma unroll
  for (int hh = 0; hh < 4; hh++) {
    int hq = kvh * 4 + hh;
    float* dst = Vout + (((size_t)(hq * B_ + b)) * S_ + s0 + sr) * HD_ + d0;
#pragma unroll
    for (int i = 0; i < 16; i += 4)
      *reinterpret_cast<float4*>(dst + i) = make_float4(v[i], v[i + 1], v[i + 2], v[i + 3]);
  }
#pragma unroll
  for (int i = 0; i < 16; i++) tile[sr][d0 + i] = v[i];
  __syncthreads();
  const int d = t >> 2;
  const int sc = (t & 3) << 4;
  union { short8 v8; u16 u[8]; } o0, o1;
#pragma unroll
  for (int i = 0; i < 8; i++) o0.u[i] = f2bf(tile[sc + i][d]);
#pragma unroll
  for (int i = 0; i < 8; i++) o1.u[i] = f2bf(tile[sc + 8 + i][d]);
  u16* dst = Vt + (((size_t)(b * KVH_ + kvh)) * HD_ + d) * S_ + s0 + sc;
  *reinterpret_cast<short8*>(dst) = o0.v8;
  *reinterpret_cast<short8*>(dst + 8) = o1.v8;
}

// ---------------- flash attention (causal, GQA) ----------------
// Block = (b, kvh, q-tile PAIR {u, 63-u}): uniform 32-34 iterations per block,
// zero tail. Wave w = head kvh*4+w, owns 2x32 q-rows (4 Q-frags: ff<2 tile A,
// ff>=2 tile B; A retires at JT_A). K/V double-buffered, 1 barrier/tile,
// stage-early. FIXED-C softmax: RMSNorm => |q.k|*scale*log2e <= 11.54 < 12
// (gain==1), so p = exp2(s*SCL2E - 12) needs NO running max / rescale; the
// softmax ratio is scale-invariant => identical result. Denominator reduced
// once after the loop.
__global__ __launch_bounds__(256, 2) void attn_fwd(const u16* __restrict__ Qn,
                                                   const u16* __restrict__ Kn,
                                                   const u16* __restrict__ Vt,
                                                   u16* __restrict__ Aout) {
  __shared__ u16 Ks[2][64 * 64];
  __shared__ u16 Vs[2][64 * 64];
  __shared__ u16 Ps[4][4][1024];  // [wave][frag][16 q-rows x 64 kv]
  const int bid = blockIdx.x;     // B_*KVH_*32
  const int u = bid & 31;
  const int kvh = (bid >> 5) & 7;
  const int b = bid >> 8;
  const int q0A = u << 5;
  const int q0B = (63 - u) << 5;
  const int JT_A = (u >> 1) + 1;
  const int JT_B = 32 - (u >> 1);
  const int tid = threadIdx.x;
  const int lane = tid & 63;
  const int wave = tid >> 6;
  const int h = kvh * 4 + wave;  // this wave's Q head
  const int ql = lane & 15;
  const int g = lane >> 4;
  const float SCL2E = 0.125f * 1.44269504088896340736f;

  // Q frags: ff=0,1 -> tile A rows q0A+16*ff+ql; ff=2,3 -> tile B
  short8 qa[4][2];
  int rowq[4];
#pragma unroll
  for (int ff = 0; ff < 4; ff++) {
    const int q0 = (ff < 2) ? q0A : q0B;
    rowq[ff] = q0 + 16 * (ff & 1) + ql;
    const u16* qb = Qn + (((size_t)(b * H_ + h)) * S_ + rowq[ff]) * HD_;
    qa[ff][0] = *reinterpret_cast<const short8*>(qb + g * 8);
    qa[ff][1] = *reinterpret_cast<const short8*>(qb + 32 + g * 8);
  }

  const f32x4 zero4 = {0.f, 0.f, 0.f, 0.f};
  f32x4 oacc[4][4];  // [dn][ff]
#pragma unroll
  for (int dn = 0; dn < 4; dn++)
#pragma unroll
    for (int ff = 0; ff < 4; ff++) oacc[dn][ff] = zero4;
  float psum[4] = {0.f, 0.f, 0.f, 0.f};

  const u16* kg = Kn + ((size_t)(b * KVH_ + kvh)) * S_ * HD_;
  const u16* vg = Vt + ((size_t)(b * KVH_ + kvh)) * HD_ * S_;

  const int c0 = tid, c1 = 256 + tid;
  const int r0 = c0 >> 3, sl0 = (c0 & 7) ^ (r0 & 7);
  const int r1 = c1 >> 3, sl1 = (c1 & 7) ^ (r1 & 7);
  const int xsw2 = (ql & 7) << 2;

  auto stage = [&](int jt, int buf) {
    const int j0 = jt << 6;
    GLDS16(kg + (size_t)(j0 + r0) * HD_ + sl0 * 8, Ks[buf] + c0 * 8);
    GLDS16(kg + (size_t)(j0 + r1) * HD_ + sl1 * 8, Ks[buf] + c1 * 8);
    GLDS16(vg + (size_t)r0 * S_ + j0 + sl0 * 8, Vs[buf] + c0 * 8);
    GLDS16(vg + (size_t)r1 * S_ + j0 + sl1 * 8, Vs[buf] + c1 * 8);
  };

  stage(0, 0);
  __syncthreads();  // drain prologue stage
  int cur = 0;
  for (int jt = 0; jt < JT_B; jt++) {
    if (jt + 1 < JT_B) stage(jt + 1, cur ^ 1);  // issue next tile early
    const int j0 = jt << 6;
    const u16* ksb = Ks[cur];
    const u16* vsb = Vs[cur];
    const bool actA = (jt < JT_A);

    // per q-tile pair: S^T = K·Q^T, then p = exp2(fma(s,SCL2E,-12)), pack->LDS
#pragma unroll
    for (int p = 0; p < 2; p++) {
      if (p == 0 && !actA) continue;
      f32x4 sc[4][2];
#pragma unroll
      for (int n = 0; n < 4; n++)
#pragma unroll
        for (int f = 0; f < 2; f++) sc[n][f] = zero4;
      __builtin_amdgcn_s_setprio(1);
#pragma unroll
      for (int ks = 0; ks < 2; ks++) {
        const int sd = ks * 4 + g;
#pragma unroll
        for (int n = 0; n < 4; n++) {
          const int r = n * 16 + ql;
          short8 kf = *reinterpret_cast<const short8*>(ksb + r * 64 + ((sd ^ (r & 7)) << 3));
          sc[n][0] = __builtin_amdgcn_mfma_f32_16x16x32_bf16(kf, qa[2 * p][ks], sc[n][0], 0, 0, 0);
          sc[n][1] = __builtin_amdgcn_mfma_f32_16x16x32_bf16(kf, qa[2 * p + 1][ks], sc[n][1], 0, 0, 0);
        }
      }
      __builtin_amdgcn_s_setprio(0);
#pragma unroll
      for (int f = 0; f < 2; f++) {
        const int ff = 2 * p + f;
        const int jtEnd = (p == 0) ? JT_A : JT_B;
        const bool diag = (jt == jtEnd - 1);
        float pv[4][4];
#pragma unroll
        for (int n = 0; n < 4; n++)
#pragma unroll
          for (int r = 0; r < 4; r++)
            pv[n][r] = exp2f(fmaf(sc[n][f][r], SCL2E, -12.0f));
        if (diag) {
#pragma unroll
          for (int n = 0; n < 4; n++)
#pragma unroll
            for (int r = 0; r < 4; r++)
              if ((j0 + n * 16 + 4 * g + r) > rowq[ff]) pv[n][r] = 0.f;
        }
        u32* pw32 = reinterpret_cast<u32*>(Ps[wave][ff]);
#pragma unroll
        for (int n = 0; n < 4; n++) {
          psum[ff] += (pv[n][0] + pv[n][1]) + (pv[n][2] + pv[n][3]);
          union { u32 w; u16 hh[2]; } c01, c23;
          c01.hh[0] = f2bf(pv[n][0]); c01.hh[1] = f2bf(pv[n][1]);
          c23.hh[0] = f2bf(pv[n][2]); c23.hh[1] = f2bf(pv[n][3]);
          const int idx = ql * 32 + (((n << 3) + (g << 1)) ^ xsw2);
          pw32[idx] = c01.w;
          pw32[idx + 1] = c23.w;
        }
      }
    }

    // read all P-frags (single LDS drain), then PV for all frags
    short8 pa[4][2];
#pragma unroll
    for (int ff = 0; ff < 4; ff++) {
      if (ff < 2 && !actA) continue;
#pragma unroll
      for (int ks = 0; ks < 2; ks++)
        pa[ff][ks] = *reinterpret_cast<const short8*>(
            Ps[wave][ff] + ql * 64 + ((32 * ks + 8 * g) ^ (xsw2 << 1)));
    }
    __builtin_amdgcn_s_setprio(1);
#pragma unroll
    for (int ks = 0; ks < 2; ks++) {
      const int sd = ks * 4 + g;
#pragma unroll
      for (int dn = 0; dn < 4; dn++) {
        const int vr = dn * 16 + ql;
        short8 vf = *reinterpret_cast<const short8*>(vsb + vr * 64 + ((sd ^ (vr & 7)) << 3));
        if (actA) {
          oacc[dn][0] = __builtin_amdgcn_mfma_f32_16x16x32_bf16(vf, pa[0][ks], oacc[dn][0], 0, 0, 0);
          oacc[dn][1] = __builtin_amdgcn_mfma_f32_16x16x32_bf16(vf, pa[1][ks], oacc[dn][1], 0, 0, 0);
        }
        oacc[dn][2] = __builtin_amdgcn_mfma_f32_16x16x32_bf16(vf, pa[2][ks], oacc[dn][2], 0, 0, 0);
        oacc[dn][3] = __builtin_amdgcn_mfma_f32_16x16x32_bf16(vf, pa[3][ks], oacc[dn][3], 0, 0, 0);
      }
    }
    __builtin_amdgcn_s_setprio(0);

    __syncthreads();  // stage(jt+1) drained + all reads of buf[cur] done
    cur ^= 1;
  }

  // final denominator reduce (once) + output
#pragma unroll
  for (int ff = 0; ff < 4; ff++) {
    float s = psum[ff];
    s += __shfl_xor(s, 16);
    s += __shfl_xor(s, 32);
    const float il = 1.0f / s;
#pragma unroll
    for (int dn = 0; dn < 4; dn++) {
      union { short4v v; u16 uu[4]; } o;
#pragma unroll
      for (int r = 0; r < 4; r++) o.uu[r] = f2bf(oacc[dn][ff][r] * il);
      u16* dst = Aout + ((size_t)b * S_ + rowq[ff]) * D_ + h * HD_ + dn * 16 + 4 * g;
      *reinterpret_cast<short4v*>(dst) = o.v;
    }
  }
}

// ---------------- launcher ----------------
extern "C" void kernel_launch(void* const* d_in, const int* in_sizes, int n_in,
                              void* d_out, int out_size, void* d_ws,
                              size_t ws_size, hipStream_t stream) {
  const float* x = (const float*)d_in[0];
  const float* wqkv = (const float*)d_in[1];
  const float* wout = (const float*)d_in[2];
  const float* gain = (const float*)d_in[3];

  float* out_attn = (float*)d_out;                       // (B,S,D) f32
  float* out_vflat = out_attn + (size_t)B_ * S_ * D_;    // (H*B,S,HD) f32

  uint8_t* w = (uint8_t*)d_ws;
  u16* xb     = (u16*)(w);                      // 16,777,216 B
  u16* wqkvb  = (u16*)(w + 16777216);           // 12,582,912 B
  u16* woutb  = (u16*)(w + 29360128);           //  8,388,608 B
  float* proj = (float*)(w + 37748736);         // 50,331,648 B
  u16* Qn     = (u16*)(w + 88080384);           // 16,777,216 B
  u16* Kn     = (u16*)(w + 104857600);          //  4,194,304 B
  u16* Vt     = (u16*)(w + 109051904);          //  4,194,304 B
  u16* attnb  = (u16*)(w + 113246208);          // 16,777,216 B
  float* tc   = (float*)(w + 130023424);        //    262,144 B
  float* ts   = (float*)(w + 130285568);        //    262,144 B
  // total: 130,547,712 B

  pack_bf16<<<4096, 256, 0, stream>>>(x, xb, B_ * S_ * D_);
  pack_bf16<<<3072, 256, 0, stream>>>(wqkv, wqkvb, PROJN * D_);
  pack_bf16<<<2048, 256, 0, stream>>>(wout, woutb, D_ * D_);
  rope_table<<<256, 256, 0, stream>>>(tc, ts);

  // proj = x @ w_qkv^T : (4096 x 3072)
  gemm_bt<<<(4096 / 128) * (3072 / 128), 256, 0, stream>>>(xb, wqkvb, proj,
                                                           4096, PROJN, 2048);
  rope_norm<<<(B_ * S_ * 40) / 4, 256, 0, stream>>>(proj, tc, ts, gain, Qn, Kn);
  vtrans<<<B_ * KVH_ * (S_ / 64), 256, 0, stream>>>(proj, Vt, out_vflat);
  // one block per q-tile PAIR: B_*KVH_*32 blocks (NOT *64 — round-6 bug)
  attn_fwd<<<B_ * KVH_ * (S_ / 64), 256, 0, stream>>>(Qn, Kn, Vt, attnb);
  // attn_out = attn @ w_out^T : (4096 x 2048)
  gemm_bt<<<(4096 / 128) * (2048 / 128), 256, 0, stream>>>(attnb, woutb,
                                                           out_attn, 4096,
                                                           2048, 2048);
}